// Round 2
// baseline (831.699 us; speedup 1.0000x reference)
//
#include <hip/hip_runtime.h>
#include <hip/hip_bf16.h>
#include <math.h>

#define D 128
#define ED 16
#define NUM_GRAPHS 64

// ---------------- CSR build ----------------

__global__ void deg_kernel(const int* __restrict__ dst, int* __restrict__ deg, int E) {
  int e = blockIdx.x * 256 + threadIdx.x;
  if (e < E) atomicAdd(&deg[dst[e]], 1);
}

__global__ __launch_bounds__(1024) void scan_kernel(const int* __restrict__ deg,
                                                    int* __restrict__ rowptr, int N) {
  __shared__ int wtot[16];
  __shared__ int wexc[16];
  __shared__ int carry_s;
  int tid = threadIdx.x;
  int lane = tid & 63, wid = tid >> 6;
  if (tid == 0) carry_s = 0;
  __syncthreads();
  for (int base = 0; base < N; base += 1024) {
    int i = base + tid;
    int v = (i < N) ? deg[i] : 0;
    int x = v;
#pragma unroll
    for (int off = 1; off < 64; off <<= 1) {
      int y = __shfl_up(x, off);
      if (lane >= off) x += y;
    }
    if (lane == 63) wtot[wid] = x;
    __syncthreads();
    if (tid == 0) {
      int run = carry_s;
#pragma unroll
      for (int w = 0; w < 16; ++w) { int t = wtot[w]; wexc[w] = run; run += t; }
      carry_s = run;
    }
    __syncthreads();
    if (i < N) rowptr[i] = wexc[wid] + x - v;  // exclusive
    __syncthreads();
  }
  if (tid == 0) rowptr[N] = carry_s;
}

__global__ void scatter_kernel(const int* __restrict__ src, const int* __restrict__ dst,
                               const int* __restrict__ rowptr, int* __restrict__ cursor,
                               int* __restrict__ csr_src, int* __restrict__ csr_eid, int E) {
  int e = blockIdx.x * 256 + threadIdx.x;
  if (e >= E) return;
  int d = dst[e];
  int pos = rowptr[d] + atomicAdd(&cursor[d], 1);
  csr_src[pos] = src[e];
  csr_eid[pos] = e;
}

// mean incoming edge_attr per node (self-loop fill value), no atomics
__global__ void loopattr_kernel(const float* __restrict__ ea, const int* __restrict__ rowptr,
                                const int* __restrict__ csr_eid, float* __restrict__ ea_mean,
                                int N) {
  int tid = threadIdx.x;
  int k = tid & 15;
  int ln = tid >> 4;  // 16 nodes per block
  int n = blockIdx.x * 16 + ln;
  if (n >= N) return;
  int beg = rowptr[n], end = rowptr[n + 1];
  float s = 0.f;
  for (int j = beg; j < end; ++j) {
    int eid = csr_eid[j];
    s += ea[eid * ED + k];
  }
  ea_mean[n * ED + k] = s / fmaxf((float)(end - beg), 1.0f);
}

// ---------------- dense xl = x@Wl, xr = x@Wr (fused) ----------------
// block: 256 threads, 64 nodes x 256 cols (Wl cols 0..127, Wr cols 128..255)
// thread: 4 nodes x 16 cols

__global__ __launch_bounds__(256) void gemm2_kernel(const float* __restrict__ x,
                                                    const float* __restrict__ Wl,
                                                    const float* __restrict__ Wr,
                                                    float* __restrict__ xl,
                                                    float* __restrict__ xr, int N) {
  __shared__ float xst[D][64];   // x tile transposed [k][node], 32KB
  __shared__ float ws[16][256];  // W k-chunk, both matrices, 16KB
  int tid = threadIdx.x;
  int base = blockIdx.x * 64;

  // stage x tile transposed: consecutive lanes -> consecutive rows (conflict-free LDS writes)
#pragma unroll
  for (int j = 0; j < 8; ++j) {
    int idx = tid + j * 256;  // 0..2047 float4s
    int row = idx & 63;
    int c4 = idx >> 6;  // 0..31
    int n = base + row;
    float4 v = make_float4(0.f, 0.f, 0.f, 0.f);
    if (n < N) v = *(const float4*)&x[(size_t)n * D + c4 * 4];
    xst[c4 * 4 + 0][row] = v.x;
    xst[c4 * 4 + 1][row] = v.y;
    xst[c4 * 4 + 2][row] = v.z;
    xst[c4 * 4 + 3][row] = v.w;
  }

  int tn = tid & 15;  // node group: nodes tn*4 .. tn*4+3
  int tc = tid >> 4;  // col group : cols tc*16 .. tc*16+15 (of 256)
  float acc[4][16];
#pragma unroll
  for (int i = 0; i < 4; ++i)
#pragma unroll
    for (int j = 0; j < 16; ++j) acc[i][j] = 0.f;

  for (int kb = 0; kb < D; kb += 16) {
    __syncthreads();
    // stage 16 k-rows of [Wl|Wr] -> ws[16][256]
#pragma unroll
    for (int j = 0; j < 4; ++j) {
      int idx = tid + j * 256;  // 0..1023 float4s
      int c4 = idx & 63;
      int kk = idx >> 6;  // 0..15
      int c = c4 * 4;
      const float* Wp = (c < D) ? &Wl[(size_t)(kb + kk) * D + c]
                                : &Wr[(size_t)(kb + kk) * D + (c - D)];
      *(float4*)&ws[kk][c] = *(const float4*)Wp;
    }
    __syncthreads();
#pragma unroll
    for (int kk = 0; kk < 16; ++kk) {
      float4 xv = *(float4*)&xst[kb + kk][tn * 4];
      float xa[4] = {xv.x, xv.y, xv.z, xv.w};
      float4 w0 = *(float4*)&ws[kk][tc * 16 + 0];
      float4 w1 = *(float4*)&ws[kk][tc * 16 + 4];
      float4 w2 = *(float4*)&ws[kk][tc * 16 + 8];
      float4 w3 = *(float4*)&ws[kk][tc * 16 + 12];
      float wa[16] = {w0.x, w0.y, w0.z, w0.w, w1.x, w1.y, w1.z, w1.w,
                      w2.x, w2.y, w2.z, w2.w, w3.x, w3.y, w3.z, w3.w};
#pragma unroll
      for (int i = 0; i < 4; ++i)
#pragma unroll
        for (int j = 0; j < 16; ++j) acc[i][j] = fmaf(xa[i], wa[j], acc[i][j]);
    }
  }

#pragma unroll
  for (int i = 0; i < 4; ++i) {
    int n = base + tn * 4 + i;
    if (n >= N) continue;
    float* outp;
    int c;
    if (tc < 8) { outp = xl; c = tc * 16; }
    else        { outp = xr; c = (tc - 8) * 16; }
#pragma unroll
    for (int j4 = 0; j4 < 4; ++j4) {
      float4 v = make_float4(acc[i][j4 * 4 + 0], acc[i][j4 * 4 + 1],
                             acc[i][j4 * 4 + 2], acc[i][j4 * 4 + 3]);
      *(float4*)&outp[(size_t)n * D + c + j4 * 4] = v;
    }
  }
}

// ---------------- fused GATv2 edge phase (one wave per dst node) ----------------
// online softmax over incoming edges + self-loop; We columns in registers.

__global__ __launch_bounds__(256) void gat_layer_kernel(
    const float* __restrict__ xl, const float* __restrict__ xr,
    const int* __restrict__ rowptr, const int* __restrict__ csr_src,
    const int* __restrict__ csr_eid, const float* __restrict__ ea,
    const float* __restrict__ ea_mean, const float* __restrict__ We,
    const float* __restrict__ att, const float* __restrict__ bias,
    float* __restrict__ y, int N) {
  int lane = threadIdx.x & 63;
  int wid = threadIdx.x >> 6;
  int n = blockIdx.x * 4 + wid;
  if (n >= N) return;

  // lane owns dims 2*lane, 2*lane+1
  float weL[ED], weH[ED];
#pragma unroll
  for (int k = 0; k < ED; ++k) {
    float2 w = *(const float2*)&We[k * D + 2 * lane];
    weL[k] = w.x;
    weH[k] = w.y;
  }
  float2 xrv = *(const float2*)&xr[(size_t)n * D + 2 * lane];
  float2 attv = *(const float2*)&att[2 * lane];
  float2 bv = *(const float2*)&bias[2 * lane];

  int beg = rowptr[n], end = rowptr[n + 1];
  float m = -INFINITY, denom = 0.f, acc0 = 0.f, acc1 = 0.f;

  for (int i = beg; i <= end; ++i) {  // i == end -> self-loop
    float2 xs;
    float av[ED];
    if (i < end) {
      int eid = csr_eid[i];
      int srcn = csr_src[i];
      xs = *(const float2*)&xl[(size_t)srcn * D + 2 * lane];
      const float4* ap = (const float4*)&ea[(size_t)eid * ED];
      float4 a0 = ap[0], a1 = ap[1], a2 = ap[2], a3 = ap[3];
      av[0] = a0.x; av[1] = a0.y; av[2] = a0.z; av[3] = a0.w;
      av[4] = a1.x; av[5] = a1.y; av[6] = a1.z; av[7] = a1.w;
      av[8] = a2.x; av[9] = a2.y; av[10] = a2.z; av[11] = a2.w;
      av[12] = a3.x; av[13] = a3.y; av[14] = a3.z; av[15] = a3.w;
    } else {
      xs = *(const float2*)&xl[(size_t)n * D + 2 * lane];
      const float4* ap = (const float4*)&ea_mean[(size_t)n * ED];
      float4 a0 = ap[0], a1 = ap[1], a2 = ap[2], a3 = ap[3];
      av[0] = a0.x; av[1] = a0.y; av[2] = a0.z; av[3] = a0.w;
      av[4] = a1.x; av[5] = a1.y; av[6] = a1.z; av[7] = a1.w;
      av[8] = a2.x; av[9] = a2.y; av[10] = a2.z; av[11] = a2.w;
      av[12] = a3.x; av[13] = a3.y; av[14] = a3.z; av[15] = a3.w;
    }
    float e0 = 0.f, e1 = 0.f;
#pragma unroll
    for (int k = 0; k < ED; ++k) {
      e0 = fmaf(av[k], weL[k], e0);
      e1 = fmaf(av[k], weH[k], e1);
    }
    float t0 = xs.x + xrv.x + e0;
    t0 = (t0 > 0.f) ? t0 : 0.2f * t0;
    float t1 = xs.y + xrv.y + e1;
    t1 = (t1 > 0.f) ? t1 : 0.2f * t1;
    float p = fmaf(t0, attv.x, t1 * attv.y);
#pragma unroll
    for (int off = 32; off > 0; off >>= 1) p += __shfl_xor(p, off);
    // online softmax update (p is wave-uniform)
    if (p > m) {
      float sc = __expf(m - p);
      denom *= sc;
      acc0 *= sc;
      acc1 *= sc;
      m = p;
    }
    float w = __expf(p - m);
    denom += w;
    acc0 = fmaf(w, xs.x, acc0);
    acc1 = fmaf(w, xs.y, acc1);
  }
  float inv = 1.0f / (denom + 1e-16f);
  float o0 = fmaxf(fmaf(acc0, inv, bv.x), 0.f);
  float o1 = fmaxf(fmaf(acc1, inv, bv.y), 0.f);
  *(float2*)&y[(size_t)n * D + 2 * lane] = make_float2(o0, o1);
}

// ---------------- global mean pool (batch is sorted) ----------------

__global__ __launch_bounds__(128) void pool_kernel(const float* __restrict__ y,
                                                   const int* __restrict__ batch,
                                                   float* __restrict__ out, int N) {
  int g = blockIdx.x;
  int d = threadIdx.x;
  __shared__ int se[2];
  if (d < 2) {
    int target = g + d;
    int lo = 0, hi = N;
    while (lo < hi) {
      int mid = (lo + hi) >> 1;
      if (batch[mid] < target) lo = mid + 1;
      else hi = mid;
    }
    se[d] = lo;
  }
  __syncthreads();
  int start = se[0], end = se[1];
  float s0 = 0.f, s1 = 0.f, s2 = 0.f, s3 = 0.f;
  int nn = start;
  for (; nn + 3 < end; nn += 4) {
    s0 += y[(size_t)(nn + 0) * D + d];
    s1 += y[(size_t)(nn + 1) * D + d];
    s2 += y[(size_t)(nn + 2) * D + d];
    s3 += y[(size_t)(nn + 3) * D + d];
  }
  for (; nn < end; ++nn) s0 += y[(size_t)nn * D + d];
  float sum = (s0 + s1) + (s2 + s3);
  float cnt = fmaxf((float)(end - start), 1.0f);
  out[g * D + d] = sum / cnt;
}

// ---------------- launch ----------------

static inline size_t alignup(size_t v) { return (v + 255) & ~(size_t)255; }

extern "C" void kernel_launch(void* const* d_in, const int* in_sizes, int n_in,
                              void* d_out, int out_size, void* d_ws, size_t ws_size,
                              hipStream_t stream) {
  const float* xnode = (const float*)d_in[0];
  const int* eidx = (const int*)d_in[1];
  const int* batch = (const int*)d_in[2];
  const float* eattr = (const float*)d_in[3];
  const float* Wl1 = (const float*)d_in[4];
  const float* Wr1 = (const float*)d_in[5];
  const float* We1 = (const float*)d_in[6];
  const float* att1 = (const float*)d_in[7];
  const float* b1 = (const float*)d_in[8];
  const float* Wl2 = (const float*)d_in[9];
  const float* Wr2 = (const float*)d_in[10];
  const float* We2 = (const float*)d_in[11];
  const float* att2 = (const float*)d_in[12];
  const float* b2 = (const float*)d_in[13];
  float* out = (float*)d_out;

  int N = in_sizes[0] / D;
  int E = in_sizes[3] / ED;
  const int* srcp = eidx;
  const int* dstp = eidx + E;

  char* p = (char*)d_ws;
  int* rowptr = (int*)p;   p += alignup((size_t)(N + 1) * 4);
  int* deg = (int*)p;      p += alignup((size_t)N * 4);
  int* cursor = (int*)p;   p += alignup((size_t)N * 4);
  int* csr_src = (int*)p;  p += alignup((size_t)E * 4);
  int* csr_eid = (int*)p;  p += alignup((size_t)E * 4);
  float* ea_mean = (float*)p; p += alignup((size_t)N * ED * 4);
  float* xlb = (float*)p;  p += alignup((size_t)N * D * 4);
  float* xrb = (float*)p;  p += alignup((size_t)N * D * 4);
  float* yb = (float*)p;   p += alignup((size_t)N * D * 4);

  hipMemsetAsync(deg, 0, (size_t)N * 4, stream);
  hipMemsetAsync(cursor, 0, (size_t)N * 4, stream);

  deg_kernel<<<(E + 255) / 256, 256, 0, stream>>>(dstp, deg, E);
  scan_kernel<<<1, 1024, 0, stream>>>(deg, rowptr, N);
  scatter_kernel<<<(E + 255) / 256, 256, 0, stream>>>(srcp, dstp, rowptr, cursor,
                                                      csr_src, csr_eid, E);
  loopattr_kernel<<<(N + 15) / 16, 256, 0, stream>>>(eattr, rowptr, csr_eid, ea_mean, N);

  // layer 1
  gemm2_kernel<<<(N + 63) / 64, 256, 0, stream>>>(xnode, Wl1, Wr1, xlb, xrb, N);
  gat_layer_kernel<<<(N + 3) / 4, 256, 0, stream>>>(xlb, xrb, rowptr, csr_src, csr_eid,
                                                    eattr, ea_mean, We1, att1, b1, yb, N);
  // layer 2
  gemm2_kernel<<<(N + 63) / 64, 256, 0, stream>>>(yb, Wl2, Wr2, xlb, xrb, N);
  gat_layer_kernel<<<(N + 3) / 4, 256, 0, stream>>>(xlb, xrb, rowptr, csr_src, csr_eid,
                                                    eattr, ea_mean, We2, att2, b2, yb, N);
  // pool
  pool_kernel<<<NUM_GRAPHS, 128, 0, stream>>>(yb, batch, out, N);
}

// Round 7
// 814.333 us; speedup vs baseline: 1.0213x; 1.0213x over previous
//
#include <hip/hip_runtime.h>
#include <hip/hip_bf16.h>
#include <math.h>

#define D 128
#define ED 16
#define NUM_GRAPHS 64
#define SCAN_CHUNK 2048

// ---------------- CSR build ----------------

__global__ void deg_kernel(const int* __restrict__ dst, int* __restrict__ deg, int E) {
  int e = blockIdx.x * 256 + threadIdx.x;
  if (e < E) atomicAdd(&deg[dst[e]], 1);
}

// hierarchical scan: 25 blocks x 2048 elems
__global__ __launch_bounds__(256) void scan_reduce_kernel(const int* __restrict__ deg,
                                                          int* __restrict__ bsum, int N) {
  int b = blockIdx.x, tid = threadIdx.x;
  int base = b * SCAN_CHUNK + tid * 8;
  int s = 0;
#pragma unroll
  for (int j = 0; j < 8; ++j) {
    int idx = base + j;
    if (idx < N) s += deg[idx];
  }
#pragma unroll
  for (int off = 1; off < 64; off <<= 1) s += __shfl_xor(s, off);
  __shared__ int ws[4];
  int lane = tid & 63, w = tid >> 6;
  if (lane == 0) ws[w] = s;
  __syncthreads();
  if (tid == 0) bsum[b] = ws[0] + ws[1] + ws[2] + ws[3];
}

__global__ void scan_bsum_kernel(const int* __restrict__ bsum, int* __restrict__ boff,
                                 int* __restrict__ rowptrN, int B) {
  int tid = threadIdx.x;  // one wave (64)
  int v = (tid < B) ? bsum[tid] : 0;
  int x = v;
#pragma unroll
  for (int off = 1; off < 64; off <<= 1) {
    int y = __shfl_up(x, off);
    if (tid >= off) x += y;
  }
  if (tid < B) boff[tid] = x - v;
  if (tid == 63) *rowptrN = x;
}

__global__ __launch_bounds__(256) void scan_write_kernel(const int* __restrict__ deg,
                                                         const int* __restrict__ boff,
                                                         int* __restrict__ rowptr, int N) {
  int b = blockIdx.x, tid = threadIdx.x;
  int lane = tid & 63, w = tid >> 6;
  int base = b * SCAN_CHUNK + tid * 8;
  int v[8];
  int s = 0;
#pragma unroll
  for (int j = 0; j < 8; ++j) {
    int idx = base + j;
    v[j] = (idx < N) ? deg[idx] : 0;
    s += v[j];
  }
  int t = s, x = t;
#pragma unroll
  for (int off = 1; off < 64; off <<= 1) {
    int y = __shfl_up(x, off);
    if (lane >= off) x += y;
  }
  __shared__ int wsum[4];
  if (lane == 63) wsum[w] = x;
  __syncthreads();
  int wexc = 0;
  for (int i = 0; i < w; ++i) wexc += wsum[i];
  int run = boff[b] + wexc + (x - t);
#pragma unroll
  for (int j = 0; j < 8; ++j) {
    int idx = base + j;
    if (idx < N) rowptr[idx] = run;
    run += v[j];
  }
}

__global__ void scatter_kernel(const int* __restrict__ src, const int* __restrict__ dst,
                               const int* __restrict__ rowptr, int* __restrict__ cursor,
                               int2* __restrict__ csr, int E) {
  int e = blockIdx.x * 256 + threadIdx.x;
  if (e >= E) return;
  int d = dst[e];
  int pos = rowptr[d] + atomicAdd(&cursor[d], 1);
  csr[pos] = make_int2(src[e], e);
}

// mean incoming edge_attr per node: wave per node, 4 edge-slots x 16 dims
__global__ __launch_bounds__(256) void loopattr_kernel(const float* __restrict__ ea,
                                                       const int* __restrict__ rowptr,
                                                       const int2* __restrict__ csr,
                                                       float* __restrict__ ea_mean, int N) {
  int lane = threadIdx.x & 63;
  int wid = threadIdx.x >> 6;
  int n = blockIdx.x * 4 + wid;
  if (n >= N) return;
  int k = lane & 15, g = lane >> 4;
  int beg = rowptr[n], end = rowptr[n + 1];
  float s = 0.f;
  for (int i = beg + g; i < end; i += 4) {
    int eid = csr[i].y;
    s += ea[(size_t)eid * ED + k];
  }
  s += __shfl_xor(s, 16);
  s += __shfl_xor(s, 32);
  if (g == 0) ea_mean[(size_t)n * ED + k] = s / fmaxf((float)(end - beg), 1.0f);
}

// ---------------- dense xl = x@Wl, xr = x@Wr (fused) ----------------

__global__ __launch_bounds__(256) void gemm2_kernel(const float* __restrict__ x,
                                                    const float* __restrict__ Wl,
                                                    const float* __restrict__ Wr,
                                                    float* __restrict__ xl,
                                                    float* __restrict__ xr, int N) {
  __shared__ float xst[D][64];   // x tile transposed [k][node], 32KB
  __shared__ float ws[16][256];  // W k-chunk, both matrices, 16KB
  int tid = threadIdx.x;
  int base = blockIdx.x * 64;

#pragma unroll
  for (int j = 0; j < 8; ++j) {
    int idx = tid + j * 256;  // 0..2047 float4s
    int row = idx & 63;
    int c4 = idx >> 6;  // 0..31
    int n = base + row;
    float4 v = make_float4(0.f, 0.f, 0.f, 0.f);
    if (n < N) v = *(const float4*)&x[(size_t)n * D + c4 * 4];
    xst[c4 * 4 + 0][row] = v.x;
    xst[c4 * 4 + 1][row] = v.y;
    xst[c4 * 4 + 2][row] = v.z;
    xst[c4 * 4 + 3][row] = v.w;
  }

  int tn = tid & 15;
  int tc = tid >> 4;
  float acc[4][16];
#pragma unroll
  for (int i = 0; i < 4; ++i)
#pragma unroll
    for (int j = 0; j < 16; ++j) acc[i][j] = 0.f;

  for (int kb = 0; kb < D; kb += 16) {
    __syncthreads();
#pragma unroll
    for (int j = 0; j < 4; ++j) {
      int idx = tid + j * 256;
      int c4 = idx & 63;
      int kk = idx >> 6;
      int c = c4 * 4;
      const float* Wp = (c < D) ? &Wl[(size_t)(kb + kk) * D + c]
                                : &Wr[(size_t)(kb + kk) * D + (c - D)];
      *(float4*)&ws[kk][c] = *(const float4*)Wp;
    }
    __syncthreads();
#pragma unroll
    for (int kk = 0; kk < 16; ++kk) {
      float4 xv = *(float4*)&xst[kb + kk][tn * 4];
      float xa[4] = {xv.x, xv.y, xv.z, xv.w};
      float4 w0 = *(float4*)&ws[kk][tc * 16 + 0];
      float4 w1 = *(float4*)&ws[kk][tc * 16 + 4];
      float4 w2 = *(float4*)&ws[kk][tc * 16 + 8];
      float4 w3 = *(float4*)&ws[kk][tc * 16 + 12];
      float wa[16] = {w0.x, w0.y, w0.z, w0.w, w1.x, w1.y, w1.z, w1.w,
                      w2.x, w2.y, w2.z, w2.w, w3.x, w3.y, w3.z, w3.w};
#pragma unroll
      for (int i = 0; i < 4; ++i)
#pragma unroll
        for (int j = 0; j < 16; ++j) acc[i][j] = fmaf(xa[i], wa[j], acc[i][j]);
    }
  }

#pragma unroll
  for (int i = 0; i < 4; ++i) {
    int n = base + tn * 4 + i;
    if (n >= N) continue;
    float* outp;
    int c;
    if (tc < 8) { outp = xl; c = tc * 16; }
    else        { outp = xr; c = (tc - 8) * 16; }
#pragma unroll
    for (int j4 = 0; j4 < 4; ++j4) {
      float4 v = make_float4(acc[i][j4 * 4 + 0], acc[i][j4 * 4 + 1],
                             acc[i][j4 * 4 + 2], acc[i][j4 * 4 + 3]);
      *(float4*)&outp[(size_t)n * D + c + j4 * 4] = v;
    }
  }
}

// ---------------- fused GATv2 edge phase (wave per dst node, 4-deep pipeline) ----

__global__ __launch_bounds__(256) void gat_layer_kernel(
    const float* __restrict__ xl, const float* __restrict__ xr,
    const int* __restrict__ rowptr, const int2* __restrict__ csr,
    const float* __restrict__ ea, const float* __restrict__ ea_mean,
    const float* __restrict__ We, const float* __restrict__ att,
    const float* __restrict__ bias, float* __restrict__ y, int N) {
  int lane = threadIdx.x & 63;
  int wid = threadIdx.x >> 6;
  int n = blockIdx.x * 4 + wid;
  if (n >= N) return;

  // lane owns dims 2*lane, 2*lane+1
  float weL[ED], weH[ED];
#pragma unroll
  for (int k = 0; k < ED; ++k) {
    float2 w = *(const float2*)&We[k * D + 2 * lane];
    weL[k] = w.x;
    weH[k] = w.y;
  }
  float2 xrv = *(const float2*)&xr[(size_t)n * D + 2 * lane];
  float2 attv = *(const float2*)&att[2 * lane];
  float2 bv = *(const float2*)&bias[2 * lane];

  int beg = rowptr[n], end = rowptr[n + 1];

  // ---- self-loop first (softmax is order-invariant) ----
  float m, denom, acc0, acc1;
  {
    float2 xsl = *(const float2*)&xl[(size_t)n * D + 2 * lane];
    const float4* ap = (const float4*)&ea_mean[(size_t)n * ED];
    float4 q0 = ap[0], q1 = ap[1], q2 = ap[2], q3 = ap[3];
    float av[16] = {q0.x, q0.y, q0.z, q0.w, q1.x, q1.y, q1.z, q1.w,
                    q2.x, q2.y, q2.z, q2.w, q3.x, q3.y, q3.z, q3.w};
    float e0 = 0.f, e1 = 0.f;
#pragma unroll
    for (int k = 0; k < ED; ++k) {
      e0 = fmaf(av[k], weL[k], e0);
      e1 = fmaf(av[k], weH[k], e1);
    }
    float t0 = xsl.x + xrv.x + e0;
    t0 = (t0 > 0.f) ? t0 : 0.2f * t0;
    float t1 = xsl.y + xrv.y + e1;
    t1 = (t1 > 0.f) ? t1 : 0.2f * t1;
    float p = fmaf(t0, attv.x, t1 * attv.y);
#pragma unroll
    for (int off = 32; off > 0; off >>= 1) p += __shfl_xor(p, off);
    m = p;
    denom = 1.f;
    acc0 = xsl.x;
    acc1 = xsl.y;
  }

  // ---- real edges, batches of 4 with all loads issued up front ----
  for (int i = beg; i < end; i += 4) {
    int cnt = end - i;
    int2 se[4];
#pragma unroll
    for (int j = 0; j < 4; ++j) {
      int idx = i + j;
      if (idx >= end) idx = end - 1;  // clamped duplicate; masked below
      se[j] = csr[idx];
    }
    float2 xs[4];
    float4 ar[4][4];
#pragma unroll
    for (int j = 0; j < 4; ++j) {
      xs[j] = *(const float2*)&xl[(size_t)se[j].x * D + 2 * lane];
      const float4* ap = (const float4*)&ea[(size_t)se[j].y * ED];
      ar[j][0] = ap[0];
      ar[j][1] = ap[1];
      ar[j][2] = ap[2];
      ar[j][3] = ap[3];
    }
#pragma unroll
    for (int j = 0; j < 4; ++j) {
      if (j < cnt) {
        float av[16] = {ar[j][0].x, ar[j][0].y, ar[j][0].z, ar[j][0].w,
                        ar[j][1].x, ar[j][1].y, ar[j][1].z, ar[j][1].w,
                        ar[j][2].x, ar[j][2].y, ar[j][2].z, ar[j][2].w,
                        ar[j][3].x, ar[j][3].y, ar[j][3].z, ar[j][3].w};
        float e0 = 0.f, e1 = 0.f;
#pragma unroll
        for (int k = 0; k < ED; ++k) {
          e0 = fmaf(av[k], weL[k], e0);
          e1 = fmaf(av[k], weH[k], e1);
        }
        float t0 = xs[j].x + xrv.x + e0;
        t0 = (t0 > 0.f) ? t0 : 0.2f * t0;
        float t1 = xs[j].y + xrv.y + e1;
        t1 = (t1 > 0.f) ? t1 : 0.2f * t1;
        float p = fmaf(t0, attv.x, t1 * attv.y);
#pragma unroll
        for (int off = 32; off > 0; off >>= 1) p += __shfl_xor(p, off);
        if (p > m) {
          float sc = __expf(m - p);
          denom *= sc;
          acc0 *= sc;
          acc1 *= sc;
          m = p;
        }
        float w = __expf(p - m);
        denom += w;
        acc0 = fmaf(w, xs[j].x, acc0);
        acc1 = fmaf(w, xs[j].y, acc1);
      }
    }
  }

  float inv = 1.0f / (denom + 1e-16f);
  float o0 = fmaxf(fmaf(acc0, inv, bv.x), 0.f);
  float o1 = fmaxf(fmaf(acc1, inv, bv.y), 0.f);
  *(float2*)&y[(size_t)n * D + 2 * lane] = make_float2(o0, o1);
}

// ---------------- global mean pool (batch sorted), 4-way row split ----------------

__global__ __launch_bounds__(128) void pool_kernel(const float* __restrict__ y,
                                                   const int* __restrict__ batch,
                                                   float* __restrict__ out, int N) {
  int g = blockIdx.x;
  int part = blockIdx.y;  // 0..3
  int d = threadIdx.x;
  __shared__ int se[2];
  if (d < 2) {
    int target = g + d;
    int lo = 0, hi = N;
    while (lo < hi) {
      int mid = (lo + hi) >> 1;
      if (batch[mid] < target) lo = mid + 1;
      else hi = mid;
    }
    se[d] = lo;
  }
  __syncthreads();
  int start = se[0], end = se[1];
  int len = end - start;
  int q = (len + 3) >> 2;
  int ps = start + part * q;
  int pe = min(ps + q, end);
  float s0 = 0.f, s1 = 0.f, s2 = 0.f, s3 = 0.f;
  int nn = ps;
  for (; nn + 3 < pe; nn += 4) {
    s0 += y[(size_t)(nn + 0) * D + d];
    s1 += y[(size_t)(nn + 1) * D + d];
    s2 += y[(size_t)(nn + 2) * D + d];
    s3 += y[(size_t)(nn + 3) * D + d];
  }
  for (; nn < pe; ++nn) s0 += y[(size_t)nn * D + d];
  float sum = (s0 + s1) + (s2 + s3);
  float cnt = fmaxf((float)len, 1.0f);
  if (ps < pe) atomicAdd(&out[g * D + d], sum / cnt);
  else if (part == 0 && len <= 0) out[g * D + d] = 0.f;  // empty graph -> 0
}

// ---------------- launch ----------------

static inline size_t alignup(size_t v) { return (v + 255) & ~(size_t)255; }

extern "C" void kernel_launch(void* const* d_in, const int* in_sizes, int n_in,
                              void* d_out, int out_size, void* d_ws, size_t ws_size,
                              hipStream_t stream) {
  const float* xnode = (const float*)d_in[0];
  const int* eidx = (const int*)d_in[1];
  const int* batch = (const int*)d_in[2];
  const float* eattr = (const float*)d_in[3];
  const float* Wl1 = (const float*)d_in[4];
  const float* Wr1 = (const float*)d_in[5];
  const float* We1 = (const float*)d_in[6];
  const float* att1 = (const float*)d_in[7];
  const float* b1 = (const float*)d_in[8];
  const float* Wl2 = (const float*)d_in[9];
  const float* Wr2 = (const float*)d_in[10];
  const float* We2 = (const float*)d_in[11];
  const float* att2 = (const float*)d_in[12];
  const float* b2 = (const float*)d_in[13];
  float* out = (float*)d_out;

  int N = in_sizes[0] / D;
  int E = in_sizes[3] / ED;
  const int* srcp = eidx;
  const int* dstp = eidx + E;
  int B = (N + SCAN_CHUNK - 1) / SCAN_CHUNK;

  char* p = (char*)d_ws;
  int* rowptr = (int*)p;   p += alignup((size_t)(N + 1) * 4);
  int* deg = (int*)p;      p += alignup((size_t)N * 4);
  int* cursor = (int*)p;   p += alignup((size_t)N * 4);
  int* bsum = (int*)p;     p += alignup((size_t)B * 4);
  int* boff = (int*)p;     p += alignup((size_t)B * 4);
  int2* csr = (int2*)p;    p += alignup((size_t)E * 8);
  float* ea_mean = (float*)p; p += alignup((size_t)N * ED * 4);
  float* xlb = (float*)p;  p += alignup((size_t)N * D * 4);
  float* xrb = (float*)p;  p += alignup((size_t)N * D * 4);
  float* yb = (float*)p;   p += alignup((size_t)N * D * 4);

  hipMemsetAsync(deg, 0, (size_t)N * 4, stream);
  hipMemsetAsync(cursor, 0, (size_t)N * 4, stream);
  hipMemsetAsync(out, 0, (size_t)NUM_GRAPHS * D * 4, stream);

  deg_kernel<<<(E + 255) / 256, 256, 0, stream>>>(dstp, deg, E);
  scan_reduce_kernel<<<B, 256, 0, stream>>>(deg, bsum, N);
  scan_bsum_kernel<<<1, 64, 0, stream>>>(bsum, boff, rowptr + N, B);
  scan_write_kernel<<<B, 256, 0, stream>>>(deg, boff, rowptr, N);
  scatter_kernel<<<(E + 255) / 256, 256, 0, stream>>>(srcp, dstp, rowptr, cursor, csr, E);
  loopattr_kernel<<<(N + 3) / 4, 256, 0, stream>>>(eattr, rowptr, csr, ea_mean, N);

  // layer 1
  gemm2_kernel<<<(N + 63) / 64, 256, 0, stream>>>(xnode, Wl1, Wr1, xlb, xrb, N);
  gat_layer_kernel<<<(N + 3) / 4, 256, 0, stream>>>(xlb, xrb, rowptr, csr, eattr, ea_mean,
                                                    We1, att1, b1, yb, N);
  // layer 2
  gemm2_kernel<<<(N + 63) / 64, 256, 0, stream>>>(yb, Wl2, Wr2, xlb, xrb, N);
  gat_layer_kernel<<<(N + 3) / 4, 256, 0, stream>>>(xlb, xrb, rowptr, csr, eattr, ea_mean,
                                                    We2, att2, b2, yb, N);
  // pool
  dim3 pgrid(NUM_GRAPHS, 4);
  pool_kernel<<<pgrid, 128, 0, stream>>>(yb, batch, out, N);
}

// Round 8
// 727.173 us; speedup vs baseline: 1.1437x; 1.1199x over previous
//
#include <hip/hip_runtime.h>
#include <hip/hip_bf16.h>
#include <math.h>

#define D 128
#define ED 16
#define NUM_GRAPHS 64
#define SCAN_CHUNK 2048

// ---------------- CSR build ----------------

__global__ void deg_kernel(const int* __restrict__ dst, int* __restrict__ deg, int E) {
  int e = blockIdx.x * 256 + threadIdx.x;
  if (e < E) atomicAdd(&deg[dst[e]], 1);
}

// hierarchical scan: blocks x 2048 elems
__global__ __launch_bounds__(256) void scan_reduce_kernel(const int* __restrict__ deg,
                                                          int* __restrict__ bsum, int N) {
  int b = blockIdx.x, tid = threadIdx.x;
  int base = b * SCAN_CHUNK + tid * 8;
  int s = 0;
#pragma unroll
  for (int j = 0; j < 8; ++j) {
    int idx = base + j;
    if (idx < N) s += deg[idx];
  }
#pragma unroll
  for (int off = 1; off < 64; off <<= 1) s += __shfl_xor(s, off);
  __shared__ int ws[4];
  int lane = tid & 63, w = tid >> 6;
  if (lane == 0) ws[w] = s;
  __syncthreads();
  if (tid == 0) bsum[b] = ws[0] + ws[1] + ws[2] + ws[3];
}

__global__ void scan_bsum_kernel(const int* __restrict__ bsum, int* __restrict__ boff,
                                 int* __restrict__ rowptrN, int B) {
  int tid = threadIdx.x;  // one wave (64)
  int v = (tid < B) ? bsum[tid] : 0;
  int x = v;
#pragma unroll
  for (int off = 1; off < 64; off <<= 1) {
    int y = __shfl_up(x, off);
    if (tid >= off) x += y;
  }
  if (tid < B) boff[tid] = x - v;
  if (tid == 63) *rowptrN = x;
}

__global__ __launch_bounds__(256) void scan_write_kernel(const int* __restrict__ deg,
                                                         const int* __restrict__ boff,
                                                         int* __restrict__ rowptr, int N) {
  int b = blockIdx.x, tid = threadIdx.x;
  int lane = tid & 63, w = tid >> 6;
  int base = b * SCAN_CHUNK + tid * 8;
  int v[8];
  int s = 0;
#pragma unroll
  for (int j = 0; j < 8; ++j) {
    int idx = base + j;
    v[j] = (idx < N) ? deg[idx] : 0;
    s += v[j];
  }
  int t = s, x = t;
#pragma unroll
  for (int off = 1; off < 64; off <<= 1) {
    int y = __shfl_up(x, off);
    if (lane >= off) x += y;
  }
  __shared__ int wsum[4];
  if (lane == 63) wsum[w] = x;
  __syncthreads();
  int wexc = 0;
  for (int i = 0; i < w; ++i) wexc += wsum[i];
  int run = boff[b] + wexc + (x - t);
#pragma unroll
  for (int j = 0; j < 8; ++j) {
    int idx = base + j;
    if (idx < N) rowptr[idx] = run;
    run += v[j];
  }
}

__global__ void scatter_kernel(const int* __restrict__ src, const int* __restrict__ dst,
                               const int* __restrict__ rowptr, int* __restrict__ cursor,
                               int2* __restrict__ csr, int E) {
  int e = blockIdx.x * 256 + threadIdx.x;
  if (e >= E) return;
  int d = dst[e];
  int pos = rowptr[d] + atomicAdd(&cursor[d], 1);
  csr[pos] = make_int2(src[e], e);
}

// mean incoming edge_attr per node: wave per node, 4 edge-slots x 16 dims
__global__ __launch_bounds__(256) void loopattr_kernel(const float* __restrict__ ea,
                                                       const int* __restrict__ rowptr,
                                                       const int2* __restrict__ csr,
                                                       float* __restrict__ ea_mean, int N) {
  int lane = threadIdx.x & 63;
  int wid = threadIdx.x >> 6;
  int n = blockIdx.x * 4 + wid;
  if (n >= N) return;
  int k = lane & 15, g = lane >> 4;
  int beg = rowptr[n], end = rowptr[n + 1];
  float s = 0.f;
  for (int i = beg + g; i < end; i += 4) {
    int eid = csr[i].y;
    s += ea[(size_t)eid * ED + k];
  }
  s += __shfl_xor(s, 16);
  s += __shfl_xor(s, 32);
  if (g == 0) ea_mean[(size_t)n * ED + k] = s / fmaxf((float)(end - beg), 1.0f);
}

// ---------------- dense xl = x@Wl, xr = x@Wr (fused) ----------------

__global__ __launch_bounds__(256) void gemm2_kernel(const float* __restrict__ x,
                                                    const float* __restrict__ Wl,
                                                    const float* __restrict__ Wr,
                                                    float* __restrict__ xl,
                                                    float* __restrict__ xr, int N) {
  __shared__ float xst[D][64];   // x tile transposed [k][node], 32KB
  __shared__ float ws[16][256];  // W k-chunk, both matrices, 16KB
  int tid = threadIdx.x;
  int base = blockIdx.x * 64;

#pragma unroll
  for (int j = 0; j < 8; ++j) {
    int idx = tid + j * 256;  // 0..2047 float4s
    int row = idx & 63;
    int c4 = idx >> 6;  // 0..31
    int n = base + row;
    float4 v = make_float4(0.f, 0.f, 0.f, 0.f);
    if (n < N) v = *(const float4*)&x[(size_t)n * D + c4 * 4];
    xst[c4 * 4 + 0][row] = v.x;
    xst[c4 * 4 + 1][row] = v.y;
    xst[c4 * 4 + 2][row] = v.z;
    xst[c4 * 4 + 3][row] = v.w;
  }

  int tn = tid & 15;
  int tc = tid >> 4;
  float acc[4][16];
#pragma unroll
  for (int i = 0; i < 4; ++i)
#pragma unroll
    for (int j = 0; j < 16; ++j) acc[i][j] = 0.f;

  for (int kb = 0; kb < D; kb += 16) {
    __syncthreads();
#pragma unroll
    for (int j = 0; j < 4; ++j) {
      int idx = tid + j * 256;
      int c4 = idx & 63;
      int kk = idx >> 6;
      int c = c4 * 4;
      const float* Wp = (c < D) ? &Wl[(size_t)(kb + kk) * D + c]
                                : &Wr[(size_t)(kb + kk) * D + (c - D)];
      *(float4*)&ws[kk][c] = *(const float4*)Wp;
    }
    __syncthreads();
#pragma unroll
    for (int kk = 0; kk < 16; ++kk) {
      float4 xv = *(float4*)&xst[kb + kk][tn * 4];
      float xa[4] = {xv.x, xv.y, xv.z, xv.w};
      float4 w0 = *(float4*)&ws[kk][tc * 16 + 0];
      float4 w1 = *(float4*)&ws[kk][tc * 16 + 4];
      float4 w2 = *(float4*)&ws[kk][tc * 16 + 8];
      float4 w3 = *(float4*)&ws[kk][tc * 16 + 12];
      float wa[16] = {w0.x, w0.y, w0.z, w0.w, w1.x, w1.y, w1.z, w1.w,
                      w2.x, w2.y, w2.z, w2.w, w3.x, w3.y, w3.z, w3.w};
#pragma unroll
      for (int i = 0; i < 4; ++i)
#pragma unroll
        for (int j = 0; j < 16; ++j) acc[i][j] = fmaf(xa[i], wa[j], acc[i][j]);
    }
  }

#pragma unroll
  for (int i = 0; i < 4; ++i) {
    int n = base + tn * 4 + i;
    if (n >= N) continue;
    float* outp;
    int c;
    if (tc < 8) { outp = xl; c = tc * 16; }
    else        { outp = xr; c = (tc - 8) * 16; }
#pragma unroll
    for (int j4 = 0; j4 < 4; ++j4) {
      float4 v = make_float4(acc[i][j4 * 4 + 0], acc[i][j4 * 4 + 1],
                             acc[i][j4 * 4 + 2], acc[i][j4 * 4 + 3]);
      *(float4*)&outp[(size_t)n * D + c + j4 * 4] = v;
    }
  }
}

// ---------------- fused GATv2 edge phase ----------------
// wave per dst node; batch-of-8 edges; ea lane-distributed (1 float/lane covers
// 4 edges) staged via per-wave LDS; xl gathers via readlane-broadcast src.

__global__ __launch_bounds__(256) void gat_layer_kernel(
    const float* __restrict__ xl, const float* __restrict__ xr,
    const int* __restrict__ rowptr, const int2* __restrict__ csr,
    const float* __restrict__ ea, const float* __restrict__ ea_mean,
    const float* __restrict__ We, const float* __restrict__ att,
    const float* __restrict__ bias, float* __restrict__ y, int N) {
  __shared__ float ea_lds[4][8][ED];  // per-wave staging, 2KB total
  int lane = threadIdx.x & 63;
  int wid = threadIdx.x >> 6;
  int n = blockIdx.x * 4 + wid;
  if (n >= N) return;

  // lane owns output dims 2*lane, 2*lane+1
  float weL[ED], weH[ED];
#pragma unroll
  for (int k = 0; k < ED; ++k) {
    float2 w = *(const float2*)&We[k * D + 2 * lane];
    weL[k] = w.x;
    weH[k] = w.y;
  }
  float2 xrv = *(const float2*)&xr[(size_t)n * D + 2 * lane];
  float2 attv = *(const float2*)&att[2 * lane];
  float2 bv = *(const float2*)&bias[2 * lane];

  int beg = rowptr[n], end = rowptr[n + 1];

  // ---- self-loop first (softmax is order-invariant) ----
  float m, denom, acc0, acc1;
  {
    float2 xsl = *(const float2*)&xl[(size_t)n * D + 2 * lane];
    const float4* ap = (const float4*)&ea_mean[(size_t)n * ED];
    float4 q0 = ap[0], q1 = ap[1], q2 = ap[2], q3 = ap[3];
    float av[16] = {q0.x, q0.y, q0.z, q0.w, q1.x, q1.y, q1.z, q1.w,
                    q2.x, q2.y, q2.z, q2.w, q3.x, q3.y, q3.z, q3.w};
    float e0 = 0.f, e1 = 0.f;
#pragma unroll
    for (int k = 0; k < ED; ++k) {
      e0 = fmaf(av[k], weL[k], e0);
      e1 = fmaf(av[k], weH[k], e1);
    }
    float t0 = xsl.x + xrv.x + e0;
    t0 = (t0 > 0.f) ? t0 : 0.2f * t0;
    float t1 = xsl.y + xrv.y + e1;
    t1 = (t1 > 0.f) ? t1 : 0.2f * t1;
    float p = fmaf(t0, attv.x, t1 * attv.y);
#pragma unroll
    for (int off = 32; off > 0; off >>= 1) p += __shfl_xor(p, off);
    m = p;
    denom = 1.f;
    acc0 = xsl.x;
    acc1 = xsl.y;
  }

  int eg = lane >> 4;   // 0..3: which edge-of-four this lane serves for ea
  int ek = lane & 15;   // which attr element

  // ---- real edges, batches of 8; all global loads issued up front ----
  for (int i = beg; i < end; i += 8) {
    int cnt = end - i;
    // 1) csr batch: lane holds edge (lane&7); duplicates are masked later
    int idx = i + (lane & 7);
    if (idx >= end) idx = end - 1;
    int2 ce = csr[idx];

    // 2) ea gather: lane serves attr ek of edges eg and 4+eg (1 float each)
    int eid0 = __shfl(ce.y, eg);
    int eid1 = __shfl(ce.y, 4 + eg);
    float a0 = ea[(size_t)eid0 * ED + ek];
    float a1 = ea[(size_t)eid1 * ED + ek];

    // 3) xl gathers: src broadcast via readlane (constant index)
    float2 xs[8];
#pragma unroll
    for (int j = 0; j < 8; ++j) {
      int sj = __shfl(ce.x, j);
      xs[j] = *(const float2*)&xl[(size_t)sj * D + 2 * lane];
    }

    // 4) stage ea to per-wave LDS (same-wave write->read, no barrier)
    ea_lds[wid][eg][ek] = a0;
    ea_lds[wid][4 + eg][ek] = a1;

    // 5) compute pre-reduce logits for all 8 edges
    float pre[8];
#pragma unroll
    for (int j = 0; j < 8; ++j) {
      const float4* eap = (const float4*)&ea_lds[wid][j][0];
      float4 q0 = eap[0], q1 = eap[1], q2 = eap[2], q3 = eap[3];
      float av[16] = {q0.x, q0.y, q0.z, q0.w, q1.x, q1.y, q1.z, q1.w,
                      q2.x, q2.y, q2.z, q2.w, q3.x, q3.y, q3.z, q3.w};
      float e0 = 0.f, e1 = 0.f;
#pragma unroll
      for (int k = 0; k < ED; ++k) {
        e0 = fmaf(av[k], weL[k], e0);
        e1 = fmaf(av[k], weH[k], e1);
      }
      float t0 = xs[j].x + xrv.x + e0;
      t0 = (t0 > 0.f) ? t0 : 0.2f * t0;
      float t1 = xs[j].y + xrv.y + e1;
      t1 = (t1 > 0.f) ? t1 : 0.2f * t1;
      pre[j] = fmaf(t0, attv.x, t1 * attv.y);
    }

    // 6) 8 independent reduction trees, interleaved for ILP
#pragma unroll
    for (int off = 32; off > 0; off >>= 1) {
#pragma unroll
      for (int j = 0; j < 8; ++j) pre[j] += __shfl_xor(pre[j], off);
    }

    // 7) serial online-softmax updates (cheap)
#pragma unroll
    for (int j = 0; j < 8; ++j) {
      if (j < cnt) {
        float p = pre[j];
        if (p > m) {
          float sc = __expf(m - p);
          denom *= sc;
          acc0 *= sc;
          acc1 *= sc;
          m = p;
        }
        float w = __expf(p - m);
        denom += w;
        acc0 = fmaf(w, xs[j].x, acc0);
        acc1 = fmaf(w, xs[j].y, acc1);
      }
    }
  }

  float inv = 1.0f / (denom + 1e-16f);
  float o0 = fmaxf(fmaf(acc0, inv, bv.x), 0.f);
  float o1 = fmaxf(fmaf(acc1, inv, bv.y), 0.f);
  *(float2*)&y[(size_t)n * D + 2 * lane] = make_float2(o0, o1);
}

// ---------------- global mean pool (batch sorted), 4-way row split ----------------

__global__ __launch_bounds__(128) void pool_kernel(const float* __restrict__ y,
                                                   const int* __restrict__ batch,
                                                   float* __restrict__ out, int N) {
  int g = blockIdx.x;
  int part = blockIdx.y;  // 0..3
  int d = threadIdx.x;
  __shared__ int se[2];
  if (d < 2) {
    int target = g + d;
    int lo = 0, hi = N;
    while (lo < hi) {
      int mid = (lo + hi) >> 1;
      if (batch[mid] < target) lo = mid + 1;
      else hi = mid;
    }
    se[d] = lo;
  }
  __syncthreads();
  int start = se[0], end = se[1];
  int len = end - start;
  int q = (len + 3) >> 2;
  int ps = start + part * q;
  int pe = min(ps + q, end);
  float s0 = 0.f, s1 = 0.f, s2 = 0.f, s3 = 0.f;
  int nn = ps;
  for (; nn + 3 < pe; nn += 4) {
    s0 += y[(size_t)(nn + 0) * D + d];
    s1 += y[(size_t)(nn + 1) * D + d];
    s2 += y[(size_t)(nn + 2) * D + d];
    s3 += y[(size_t)(nn + 3) * D + d];
  }
  for (; nn < pe; ++nn) s0 += y[(size_t)nn * D + d];
  float sum = (s0 + s1) + (s2 + s3);
  float cnt = fmaxf((float)len, 1.0f);
  if (ps < pe) atomicAdd(&out[g * D + d], sum / cnt);
  else if (part == 0 && len <= 0) out[g * D + d] = 0.f;  // empty graph -> 0
}

// ---------------- launch ----------------

static inline size_t alignup(size_t v) { return (v + 255) & ~(size_t)255; }

extern "C" void kernel_launch(void* const* d_in, const int* in_sizes, int n_in,
                              void* d_out, int out_size, void* d_ws, size_t ws_size,
                              hipStream_t stream) {
  const float* xnode = (const float*)d_in[0];
  const int* eidx = (const int*)d_in[1];
  const int* batch = (const int*)d_in[2];
  const float* eattr = (const float*)d_in[3];
  const float* Wl1 = (const float*)d_in[4];
  const float* Wr1 = (const float*)d_in[5];
  const float* We1 = (const float*)d_in[6];
  const float* att1 = (const float*)d_in[7];
  const float* b1 = (const float*)d_in[8];
  const float* Wl2 = (const float*)d_in[9];
  const float* Wr2 = (const float*)d_in[10];
  const float* We2 = (const float*)d_in[11];
  const float* att2 = (const float*)d_in[12];
  const float* b2 = (const float*)d_in[13];
  float* out = (float*)d_out;

  int N = in_sizes[0] / D;
  int E = in_sizes[3] / ED;
  const int* srcp = eidx;
  const int* dstp = eidx + E;
  int B = (N + SCAN_CHUNK - 1) / SCAN_CHUNK;

  char* p = (char*)d_ws;
  int* rowptr = (int*)p;   p += alignup((size_t)(N + 1) * 4);
  int* deg = (int*)p;      p += alignup((size_t)N * 4);
  int* cursor = (int*)p;   p += alignup((size_t)N * 4);
  int* bsum = (int*)p;     p += alignup((size_t)B * 4);
  int* boff = (int*)p;     p += alignup((size_t)B * 4);
  int2* csr = (int2*)p;    p += alignup((size_t)E * 8);
  float* ea_mean = (float*)p; p += alignup((size_t)N * ED * 4);
  float* xlb = (float*)p;  p += alignup((size_t)N * D * 4);
  float* xrb = (float*)p;  p += alignup((size_t)N * D * 4);
  float* yb = (float*)p;   p += alignup((size_t)N * D * 4);

  hipMemsetAsync(deg, 0, (size_t)N * 4, stream);
  hipMemsetAsync(cursor, 0, (size_t)N * 4, stream);
  hipMemsetAsync(out, 0, (size_t)NUM_GRAPHS * D * 4, stream);

  deg_kernel<<<(E + 255) / 256, 256, 0, stream>>>(dstp, deg, E);
  scan_reduce_kernel<<<B, 256, 0, stream>>>(deg, bsum, N);
  scan_bsum_kernel<<<1, 64, 0, stream>>>(bsum, boff, rowptr + N, B);
  scan_write_kernel<<<B, 256, 0, stream>>>(deg, boff, rowptr, N);
  scatter_kernel<<<(E + 255) / 256, 256, 0, stream>>>(srcp, dstp, rowptr, cursor, csr, E);
  loopattr_kernel<<<(N + 3) / 4, 256, 0, stream>>>(eattr, rowptr, csr, ea_mean, N);

  // layer 1
  gemm2_kernel<<<(N + 63) / 64, 256, 0, stream>>>(xnode, Wl1, Wr1, xlb, xrb, N);
  gat_layer_kernel<<<(N + 3) / 4, 256, 0, stream>>>(xlb, xrb, rowptr, csr, eattr, ea_mean,
                                                    We1, att1, b1, yb, N);
  // layer 2
  gemm2_kernel<<<(N + 63) / 64, 256, 0, stream>>>(yb, Wl2, Wr2, xlb, xrb, N);
  gat_layer_kernel<<<(N + 3) / 4, 256, 0, stream>>>(xlb, xrb, rowptr, csr, eattr, ea_mean,
                                                    We2, att2, b2, yb, N);
  // pool
  dim3 pgrid(NUM_GRAPHS, 4);
  pool_kernel<<<pgrid, 128, 0, stream>>>(yb, batch, out, N);
}